// Round 1
// baseline (496.718 us; speedup 1.0000x reference)
//
#include <hip/hip_runtime.h>

// Problem constants (fixed by setup_inputs)
#define CIN   16
#define COUT  32
#define BATCH 2
#define DSP   32
#define HSP   128
#define WSP   128
// Tiling: tile = 4 (z) x 16 (y) x 16 (x) = 1024 voxels; 8x8x8 tiles per batch
#define TILES_PER_B 512
#define NTILES      1024            // BATCH * 512
#define BIN_CAP     256
#define LST_CAP     512
#define COG         8               // c_out per block (4 groups)

// ---------------- dedup: last-write-wins voxel -> point map ----------------
__global__ void k_dedup(const int* __restrict__ coords, int* __restrict__ map, int n) {
    int p = blockIdx.x * 256 + threadIdx.x;
    if (p >= n) return;
    int b = coords[p*4+0], z = coords[p*4+1], y = coords[p*4+2], x = coords[p*4+3];
    int vox = ((b*DSP + z)*HSP + y)*WSP + x;
    atomicMax(&map[vox], p);
}

// ---------------- bin winning points by spatial tile ----------------
__global__ void k_bin(const int* __restrict__ coords, const int* __restrict__ map,
                      int* __restrict__ binCnt, int* __restrict__ bins, int n) {
    int p = blockIdx.x * 256 + threadIdx.x;
    if (p >= n) return;
    int b = coords[p*4+0], z = coords[p*4+1], y = coords[p*4+2], x = coords[p*4+3];
    int vox = ((b*DSP + z)*HSP + y)*WSP + x;
    if (map[vox] != p) return;                       // only the winner scatters
    int tile = ((b*8 + (z>>2))*8 + (y>>4))*8 + (x>>4);
    int slot = atomicAdd(&binCnt[tile], 1);
    if (slot < BIN_CAP) bins[tile*BIN_CAP + slot] = p;
}

// ---------------- repack weights: dst[kidx][grp][ci][col8] ----------------
// kernel[co][ci][kd][kh][kw] = weight_flat[co*432 + ci*27 + kidx]  (pure reshape)
__global__ void k_repack(const float* __restrict__ w, float* __restrict__ wr) {
    int i = blockIdx.x * 256 + threadIdx.x;          // 27*4*16*8 = 13824
    if (i >= 27*CIN*COUT) return;
    int col = i & 7, ci = (i>>3) & 15, g = (i>>7) & 3, kidx = i >> 9;
    int co = g*COG + col;
    wr[i] = w[(co*CIN + ci)*27 + kidx];
}

// ---------------- tiled scatter conv ----------------
__global__ __launch_bounds__(256, 4) void k_conv(
    const float* __restrict__ feat, const int* __restrict__ coords,
    const float* __restrict__ wr,   const float* __restrict__ bias,
    const int* __restrict__ binCnt, const int* __restrict__ bins,
    float* __restrict__ out)
{
    __shared__ float acc[COG*1024];   // 32 KB
    __shared__ int   lst[LST_CAP];
    __shared__ int   lcnt;

    int bid  = blockIdx.x;
    int g    = bid & 3;               // c_out group
    int tile = bid >> 2;
    int txi = tile & 7, tyi = (tile>>3) & 7, tzi = (tile>>6) & 7, b = tile >> 9;
    int z0 = tzi << 2, y0 = tyi << 4, x0 = txi << 4;

    for (int i = threadIdx.x; i < COG*1024; i += 256) acc[i] = 0.f;
    if (threadIdx.x == 0) lcnt = 0;
    __syncthreads();

    // gather halo points (own tile + 26 neighbors, +-1 voxel halo)
    for (int dz = -1; dz <= 1; ++dz)
    for (int dy = -1; dy <= 1; ++dy)
    for (int dx = -1; dx <= 1; ++dx) {
        int nz = tzi + dz, ny = tyi + dy, nx = txi + dx;
        if ((unsigned)nz > 7u || (unsigned)ny > 7u || (unsigned)nx > 7u) continue;
        int nt  = ((b*8 + nz)*8 + ny)*8 + nx;
        int cnt = binCnt[nt]; if (cnt > BIN_CAP) cnt = BIN_CAP;
        for (int i = threadIdx.x; i < cnt; i += 256) {
            int p  = bins[nt*BIN_CAP + i];
            int pz = coords[p*4+1], py = coords[p*4+2], px = coords[p*4+3];
            if (pz >= z0-1 && pz <= z0+4 && py >= y0-1 && py <= y0+16 &&
                px >= x0-1 && px <= x0+16) {
                int s = atomicAdd(&lcnt, 1);
                if (s < LST_CAP) lst[s] = p;
            }
        }
    }
    __syncthreads();
    int M = lcnt; if (M > LST_CAP) M = LST_CAP;

    for (int base = 0; base < M; base += 256) {
        int idx = base + (int)threadIdx.x;
        bool valid = idx < M;
        if (__ballot(valid) == 0ull) continue;       // whole wave idle -> skip
        int p = valid ? lst[idx] : lst[0];
        const float* fp = feat + (long)p * CIN;
        float f[CIN];
        #pragma unroll
        for (int ci = 0; ci < CIN; ++ci) f[ci] = fp[ci];
        int pz = coords[p*4+1], py = coords[p*4+2], px = coords[p*4+3];
        int lz = pz - z0 + 1, ly = py - y0 + 1, lx = px - x0 + 1;

        #pragma unroll 1
        for (int kd = 0; kd < 3; ++kd)
        #pragma unroll 1
        for (int kh = 0; kh < 3; ++kh)
        #pragma unroll 1
        for (int kw = 0; kw < 3; ++kw) {
            int tz = lz - kd, ty = ly - kh, tx = lx - kw;   // target local voxel
            bool in = valid && ((unsigned)tz < 4u) && ((unsigned)ty < 16u)
                            && ((unsigned)tx < 16u);
            int kidx = (kd*3 + kh)*3 + kw;
            const float* wk = wr + (kidx*4 + g)*(CIN*COG);  // wave-uniform address
            float c[COG] = {0,0,0,0,0,0,0,0};
            #pragma unroll
            for (int ci = 0; ci < CIN; ++ci) {
                float fv = f[ci];
                #pragma unroll
                for (int co = 0; co < COG; ++co) c[co] += wk[ci*COG + co] * fv;
            }
            if (in) {
                int lv = (tz << 8) + (ty << 4) + tx;
                #pragma unroll
                for (int co = 0; co < COG; ++co)
                    atomicAdd(&acc[co*1024 + lv], c[co]);
            }
        }
    }
    __syncthreads();

    // writeback: out = relu(acc + bias), float4 stores, written exactly once
    int cobase = g * COG;
    for (int i4 = (int)threadIdx.x; i4 < (COG*1024)/4; i4 += 256) {
        int i  = i4 * 4;
        int co = i >> 10;
        int lv = i & 1023;
        float4 v = *reinterpret_cast<const float4*>(&acc[co*1024 + lv]);
        float bv = bias[cobase + co];
        v.x = fmaxf(v.x + bv, 0.f); v.y = fmaxf(v.y + bv, 0.f);
        v.z = fmaxf(v.z + bv, 0.f); v.w = fmaxf(v.w + bv, 0.f);
        int tz = lv >> 8, ty = (lv >> 4) & 15, tx = lv & 15;
        long o = ((((long)b*COUT + cobase + co)*DSP + (z0 + tz))*HSP + (y0 + ty))*WSP
                 + (x0 + tx);
        *reinterpret_cast<float4*>(&out[o]) = v;
    }
}

extern "C" void kernel_launch(void* const* d_in, const int* in_sizes, int n_in,
                              void* d_out, int out_size, void* d_ws, size_t ws_size,
                              hipStream_t stream) {
    const float* feat   = (const float*)d_in[0];
    const int*   coords = (const int*)d_in[1];
    const float* weight = (const float*)d_in[2];
    const float* bias   = (const float*)d_in[3];
    float* out = (float*)d_out;
    int n = in_sizes[0] / CIN;                       // number of points

    // workspace layout
    int* map    = (int*)d_ws;                        // 1,048,576 ints
    int* binCnt = map + BATCH*DSP*HSP*WSP;           // 1024 ints
    int* bins   = binCnt + NTILES;                   // 1024*256 ints
    float* wr   = (float*)(bins + NTILES*BIN_CAP);   // 13824 floats

    hipMemsetAsync(map, 0xFF, (size_t)BATCH*DSP*HSP*WSP*sizeof(int), stream); // -1
    hipMemsetAsync(binCnt, 0, NTILES*sizeof(int), stream);

    int nb = (n + 255) / 256;
    k_dedup <<<nb, 256, 0, stream>>>(coords, map, n);
    k_bin   <<<nb, 256, 0, stream>>>(coords, map, binCnt, bins, n);
    k_repack<<<(27*CIN*COUT + 255)/256, 256, 0, stream>>>(weight, wr);
    k_conv  <<<NTILES*4, 256, 0, stream>>>(feat, coords, wr, bias, binCnt, bins, out);
}